// Round 12
// baseline (74.907 us; speedup 1.0000x reference)
//
#include <hip/hip_runtime.h>
#include <math.h>

// FreqEmbedding: seq [16,512,64] f32 -> out [16,512,65,64] f32
// reflect-pad(64) -> hanning(128) frames -> rfft(128) -> complex standardize
// over (L,F) per (B,C) -> abs.
//
// Pass 0 (pad): materialize reflect-padded input [16,640,64] (proven).
// Pass A (reduce): Parseval + symmetry identities (4 dot products) (proven).
// Pass B (write): 4-THREADS-PER-FFT, LDS-exchanged (cuFFT-style).
//   R4-R11 law: monolithic 64-pt FFT = min VALU but 128-f32 state -> ~2
//   waves/SIMD (AGPR parking), ~35% busy, unhidden stores. All 1-thread
//   repackagings hit VALU-duplication instead (R6/R9/R10/R11).
//   Here: thread (n4,c) holds 16 points. Strides 1,2,4,8 in-register
//   (contiguous chunk, literal twiddles); LDS transpose; strides 16,32
//   in-register (strided residues, wave-uniform twiddles via scalar loads);
//   LDS Z-exchange for the k<->64-k unpack partner. Same butterfly count
//   as monolithic, state ~60 VGPR, 20 waves/CU, coalesced 256B LDS/global.

#define B_ 16
#define L_ 512
#define C_ 64
#define W_ 128
#define F_ 65
#define LP 640  // padded length
#define NLF (L_ * F_)  // 33280

// ---------- compile-time trig tables ----------
constexpr double kPI = 3.14159265358979323846;

constexpr double csin_(double x) {
  while (x > kPI) x -= 2.0 * kPI;
  while (x < -kPI) x += 2.0 * kPI;
  double t = x, s = x, x2 = x * x;
  for (int i = 1; i <= 24; ++i) {
    t *= -x2 / ((2.0 * i) * (2.0 * i + 1.0));
    s += t;
  }
  return s;
}
constexpr double ccos_(double x) { return csin_(kPI / 2.0 - x); }

constexpr int bitrev4(int n) {
  int r = 0;
  for (int i = 0; i < 4; ++i) r |= ((n >> i) & 1) << (3 - i);
  return r;
}

struct Tables {
  float win[128];           // hanning w_n
  float walt[128];          // (-1)^n w_n
  float w2[128];            // w_n^2
  float wg[128];            // w_n * G_n
  float t64r[32], t64i[32]; // exp(-2*pi*i*j/64), j=0..31
  float c128r[64], c128i[64]; // exp(-2*pi*i*k/128), k=0..63
  constexpr Tables()
      : win(), walt(), w2(), wg(), t64r(), t64i(), c128r(), c128i() {
    for (int n = 0; n < 128; ++n) {
      const double wd = 0.5 - 0.5 * ccos_(2.0 * kPI * n / 127.0);
      win[n] = (float)wd;
      walt[n] = (n & 1) ? (float)(-wd) : (float)wd;
      w2[n] = (float)(wd * wd);
      if (n == 0) {
        wg[n] = 0.0f;
      } else {
        const double G = csin_(kPI * n / 2.0) * csin_(65.0 * kPI * n / 128.0) /
                         csin_(kPI * n / 128.0);
        wg[n] = (float)(wd * G);
      }
    }
    for (int j = 0; j < 32; ++j) {
      t64r[j] = (float)ccos_(2.0 * kPI * j / 64.0);
      t64i[j] = (float)(-csin_(2.0 * kPI * j / 64.0));
    }
    for (int k = 0; k < 64; ++k) {
      c128r[k] = (float)ccos_(2.0 * kPI * k / 128.0);
      c128i[k] = (float)(-csin_(2.0 * kPI * k / 128.0));
    }
  }
};
constexpr Tables TBL{};

// branchless reflect into [0,512) for t in [-64, 575]
__device__ __forceinline__ int refl(int t) {
  const int a = max(t, -t);
  return min(a, 1022 - a);
}

__device__ __forceinline__ float fast_sqrt(float x) {
  float r;
  asm("v_sqrt_f32 %0, %1" : "=v"(r) : "v"(x));
  return r;
}

// ---------------- Pass 0: materialize reflect-padded input ----------------
__global__ void __launch_bounds__(256)
fe_pad_kernel(const float* __restrict__ seq, float* __restrict__ pad) {
  const int idx = blockIdx.x * 256 + threadIdx.x;  // b*LP*C + t*C + c
  const int c = idx & 63;
  const int row = idx >> 6;  // b*LP + t
  const int b = row / LP;
  const int t = row - b * LP;
  const int s = refl(t - 64);
  pad[idx] = seq[(b * L_ + s) * C_ + c];
}

// ws layout (floats): [0..1023] sum_re, [1024..2047] sum_im, [2048..3071] sum_sq,
//                     [4096 ..] padded input [16][640][64]
// ---------------- Pass A: Parseval reduce (on padded input) ----------------
__global__ void __launch_bounds__(256)
fe_reduce_kernel(const float* __restrict__ pad, float* __restrict__ acc) {
  const int p = blockIdx.x * 4 + (threadIdx.x >> 6);
  const int b = __builtin_amdgcn_readfirstlane(p >> 9);
  const int l = __builtin_amdgcn_readfirstlane(p & (L_ - 1));
  const int c = threadIdx.x & 63;

  const float* base = pad + ((size_t)(b * LP + l)) * C_ + c;

  float x0 = 0.f, x64 = 0.f, p2 = 0.f, d2 = 0.f;
#pragma unroll
  for (int n = 0; n < 128; ++n) {
    const float v = base[n * C_];
    x0 += TBL.win[n] * v;
    x64 += TBL.walt[n] * v;
    const float wv = TBL.w2[n] * v;
    p2 += wv * v;
    d2 += TBL.wg[n] * v;
  }

  const float sre = 0.5f * (x0 + x64);
  const float sim = -d2;
  const float ssq = 64.0f * p2 + 0.5f * (x0 * x0 + x64 * x64);

  __shared__ float red[3][256];
  const int tid = threadIdx.x;
  red[0][tid] = sre;
  red[1][tid] = sim;
  red[2][tid] = ssq;
  __syncthreads();
  if (tid < 64) {
    const float a0 = red[0][tid] + red[0][tid + 64] + red[0][tid + 128] + red[0][tid + 192];
    const float a1 = red[1][tid] + red[1][tid + 64] + red[1][tid + 128] + red[1][tid + 192];
    const float a2 = red[2][tid] + red[2][tid + 64] + red[2][tid + 128] + red[2][tid + 192];
    const int g = b * C_ + tid;
    unsafeAtomicAdd(&acc[g], a0);
    unsafeAtomicAdd(&acc[1024 + g], a1);
    unsafeAtomicAdd(&acc[2048 + g], a2);
  }
}

// ---------------- Pass B: 4-thread cooperative FFT + write ----------------
__global__ void __launch_bounds__(256)
fe_write_kernel(const float* __restrict__ pad, const float* __restrict__ acc,
                float* __restrict__ out) {
  __shared__ float2 lds[64][64];  // [point][channel], 32 KB

  const int tid = threadIdx.x;
  const int n4 = __builtin_amdgcn_readfirstlane(tid >> 6);  // chunk id (wave id)
  const int c = tid & 63;
  const int frame = __builtin_amdgcn_readfirstlane(blockIdx.x);  // b*L + l
  const int b = frame >> 9;

  // fused finalize: true-scale sums -> constants matching the 2x bins
  const int g = b * C_ + c;
  const float invN = 1.0f / (float)NLF;
  const float sr = acc[g] * invN;
  const float si = acc[1024 + g] * invN;
  const float qq = acc[2048 + g] * invN;
  const float var = qq - sr * sr - si * si;
  const float mr = 2.0f * sr;
  const float mi = 2.0f * si;
  const float is = 0.5f * rsqrtf(var);

  const int l = frame & 511;
  const float* base = pad + ((size_t)(b * LP + l)) * C_ + c;
  float* obase = out + ((size_t)frame * F_) * C_ + c;

  const int brn4 = ((n4 & 1) << 1) | (n4 >> 1);  // bitrev2(n4), SGPR

  // ---- load 16 complex points: array slot a = 16*n4 + i holds point
  //      q = bitrev6(a) = 4*bitrev4(i) + brn4; samples (2q, 2q+1), windowed.
  float zr[16], zi[16];
#pragma unroll
  for (int i = 0; i < 16; ++i) {
    const int row = 8 * bitrev4(i) + 2 * brn4;  // = 2q
    zr[i] = TBL.win[row] * base[row * C_];
    zi[i] = TBL.win[row + 1] * base[(row + 1) * C_];
  }

  // ---- phase 1: strides 1,2,4,8 inside the contiguous 16-chunk.
  //      chunk base 16*n4 === 0 (mod 16) => twiddle j = i mod half (literal).
#pragma unroll
  for (int s = 0; s < 4; ++s) {
    const int half = 1 << s;
    const int len = half << 1;
#pragma unroll
    for (int j = 0; j < half; ++j) {
      const float wr = TBL.t64r[j << (5 - s)];
      const float wi = TBL.t64i[j << (5 - s)];
#pragma unroll
      for (int b2 = 0; b2 < 16; b2 += len) {
        const int a = b2 + j;
        const int bb = a + half;
        const float tr = wr * zr[bb] - wi * zi[bb];
        const float ti = wr * zi[bb] + wi * zr[bb];
        zr[bb] = zr[a] - tr;
        zi[bb] = zi[a] - ti;
        zr[a] += tr;
        zi[a] += ti;
      }
    }
  }

  // ---- transpose via LDS: contiguous chunk -> strided residues ----
#pragma unroll
  for (int i = 0; i < 16; ++i)
    lds[16 * n4 + i][c] = make_float2(zr[i], zi[i]);
  __syncthreads();
  // reg idx 4*u+t holds array pos P(u,t) = 4*n4 + u + 16*t
#pragma unroll
  for (int u = 0; u < 4; ++u)
#pragma unroll
    for (int t = 0; t < 4; ++t) {
      const float2 v = lds[4 * n4 + u + 16 * t][c];
      zr[4 * u + t] = v.x;
      zi[4 * u + t] = v.y;
    }
  __syncthreads();  // all transpose reads done before Z overwrites

  // ---- phase 2: strides 16, 32 (in-register; twiddles wave-uniform) ----
#pragma unroll
  for (int u = 0; u < 4; ++u) {
    // stage half=16: pairs (t=0,1) and (t=2,3); tw = e64[(4n4+u)*2]
    {
      const int jj = (4 * n4 + u) << 1;
      const float wr = TBL.t64r[jj], wi = TBL.t64i[jj];
#pragma unroll
      for (int t0 = 0; t0 < 4; t0 += 2) {
        const int a = 4 * u + t0, bb = a + 1;
        const float tr = wr * zr[bb] - wi * zi[bb];
        const float ti = wr * zi[bb] + wi * zr[bb];
        zr[bb] = zr[a] - tr;
        zi[bb] = zi[a] - ti;
        zr[a] += tr;
        zi[a] += ti;
      }
    }
    // stage half=32: pairs (t=0,2) tw e64[4n4+u]; (t=1,3) tw e64[4n4+u+16]
#pragma unroll
    for (int t0 = 0; t0 < 2; ++t0) {
      const int jj = 4 * n4 + u + 16 * t0;
      const float wr = TBL.t64r[jj], wi = TBL.t64i[jj];
      const int a = 4 * u + t0, bb = a + 2;
      const float tr = wr * zr[bb] - wi * zi[bb];
      const float ti = wr * zi[bb] + wi * zr[bb];
      zr[bb] = zr[a] - tr;
      zi[bb] = zi[a] - ti;
      zr[a] += tr;
      zi[a] += ti;
    }
  }
  // reg 4u+t now holds Z[P(u,t)], P = 4*n4 + u + 16*t

  // ---- Z-exchange for unpack partners ----
#pragma unroll
  for (int u = 0; u < 4; ++u)
#pragma unroll
    for (int t = 0; t < 4; ++t)
      lds[4 * n4 + u + 16 * t][c] = make_float2(zr[4 * u + t], zi[4 * u + t]);
  __syncthreads();

  auto emit = [&](int foff, float Xr, float Xi) {
    const float dr = Xr - mr;
    const float di = Xi - mi;
    const float amp = fast_sqrt(__builtin_fmaf(dr, dr, di * di)) * is;
    __builtin_nontemporal_store(amp, obase + foff);
  };

  // ---- unpack + emit: bin k = P uses Z[P] (reg) and Z[64-P] (LDS).
  //      Direct c128[k] formula valid for all k in 1..63 (incl. 32). ----
#pragma unroll
  for (int u = 0; u < 4; ++u)
#pragma unroll
    for (int t = 0; t < 4; ++t) {
      const int idx = 4 * u + t;
      const int P = 4 * n4 + u + 16 * t;  // wave-uniform + literal
      if (n4 == 0 && u == 0 && t == 0) {
        // P == 0: bins 0 and 64 from Z[0]
        emit(0, 2.0f * (zr[0] + zi[0]), 0.0f);
        emit(64 * C_, 2.0f * (zr[0] - zi[0]), 0.0f);
      } else {
        const float2 o = lds[64 - P][c];
        const float Er = zr[idx] + o.x;
        const float Ei = zi[idx] - o.y;
        const float Or = zi[idx] + o.y;
        const float Oi = o.x - zr[idx];
        const float cr = TBL.c128r[P], ci = TBL.c128i[P];
        const float wOr = cr * Or - ci * Oi;
        const float wOi = cr * Oi + ci * Or;
        emit(P * C_, Er + wOr, Ei + wOi);
      }
    }
}

extern "C" void kernel_launch(void* const* d_in, const int* in_sizes, int n_in,
                              void* d_out, int out_size, void* d_ws, size_t ws_size,
                              hipStream_t stream) {
  const float* seq = (const float*)d_in[0];
  float* out = (float*)d_out;
  float* ws = (float*)d_ws;
  float* acc = ws;          // 3072 floats
  float* pad = ws + 4096;   // 16*640*64 = 655360 floats (2.62 MB)

  hipMemsetAsync(acc, 0, 3072 * sizeof(float), stream);

  fe_pad_kernel<<<(B_ * LP * C_) / 256, 256, 0, stream>>>(seq, pad);
  fe_reduce_kernel<<<(B_ * L_) / 4, 256, 0, stream>>>(pad, acc);
  // one frame per block, 4 threads per channel-FFT
  fe_write_kernel<<<B_ * L_, 256, 0, stream>>>(pad, acc, out);
}

// Round 13
// 62.894 us; speedup vs baseline: 1.1910x; 1.1910x over previous
//
#include <hip/hip_runtime.h>
#include <math.h>

// FreqEmbedding: seq [16,512,64] f32 -> out [16,512,65,64] f32
// reflect-pad(64) -> hanning(128) frames -> rfft(128) -> complex standardize
// over (L,F) per (B,C) -> abs.
//
// Pass 0 (pad): materialize reflect-padded input [16,640,64] (proven).
// Pass A (reduce): Parseval + symmetry identities (4 dot products) (proven).
// Pass B (write): monolithic 64-pt FFT per thread (min VALU; every
//   restructure R6/R9-R12 regressed), single compact body.
//   ROUND 13 SINGLE CHANGE: nt-stores -> PLAIN CACHED stores. Theory: the
//   nontemporal/streaming write path caps ~2.9 TB/s (our write kernel, R5's
//   spill stream), while cached writes (harness fillBuffer) sustain
//   6.1-6.8 TB/s on this chip. The write kernel is store-path-bound, not
//   VALU/occupancy-bound -- which is why all compute restructures failed.

#define B_ 16
#define L_ 512
#define C_ 64
#define W_ 128
#define F_ 65
#define LP 640  // padded length
#define NLF (L_ * F_)  // 33280

// ---------- compile-time trig tables (fold to VALU literals) ----------
constexpr double kPI = 3.14159265358979323846;

constexpr double csin_(double x) {
  while (x > kPI) x -= 2.0 * kPI;
  while (x < -kPI) x += 2.0 * kPI;
  double t = x, s = x, x2 = x * x;
  for (int i = 1; i <= 24; ++i) {
    t *= -x2 / ((2.0 * i) * (2.0 * i + 1.0));
    s += t;
  }
  return s;
}
constexpr double ccos_(double x) { return csin_(kPI / 2.0 - x); }

constexpr int bitrev6(int n) {
  int r = 0;
  for (int i = 0; i < 6; ++i) r |= ((n >> i) & 1) << (5 - i);
  return r;
}

struct Tables {
  float win[128];         // hanning w_n
  float walt[128];        // (-1)^n w_n
  float w2[128];          // w_n^2
  float wg[128];          // w_n * G_n
  float twr[32], twi[32]; // exp(-2*pi*i*j/64)
  float cur[32], cui[32]; // exp(-2*pi*i*k/128), k=0..31
  constexpr Tables() : win(), walt(), w2(), wg(), twr(), twi(), cur(), cui() {
    for (int n = 0; n < 128; ++n) {
      const double wd = 0.5 - 0.5 * ccos_(2.0 * kPI * n / 127.0);
      win[n] = (float)wd;
      walt[n] = (n & 1) ? (float)(-wd) : (float)wd;
      w2[n] = (float)(wd * wd);
      if (n == 0) {
        wg[n] = 0.0f;
      } else {
        // G_n = sin(pi n/2) * sin(65 pi n/128) / sin(pi n/128)
        const double G = csin_(kPI * n / 2.0) * csin_(65.0 * kPI * n / 128.0) /
                         csin_(kPI * n / 128.0);
        wg[n] = (float)(wd * G);
      }
    }
    for (int j = 0; j < 32; ++j) {
      twr[j] = (float)ccos_(2.0 * kPI * j / 64.0);
      twi[j] = (float)(-csin_(2.0 * kPI * j / 64.0));
    }
    for (int k = 0; k < 32; ++k) {
      cur[k] = (float)ccos_(2.0 * kPI * k / 128.0);
      cui[k] = (float)(-csin_(2.0 * kPI * k / 128.0));
    }
  }
};
constexpr Tables TBL{};

// branchless reflect into [0,512) for t in [-64, 575]
__device__ __forceinline__ int refl(int t) {
  const int a = max(t, -t);
  return min(a, 1022 - a);
}

__device__ __forceinline__ float fast_sqrt(float x) {
  float r;
  asm("v_sqrt_f32 %0, %1" : "=v"(r) : "v"(x));
  return r;
}

// ---------------- Pass 0: materialize reflect-padded input ----------------
__global__ void __launch_bounds__(256)
fe_pad_kernel(const float* __restrict__ seq, float* __restrict__ pad) {
  const int idx = blockIdx.x * 256 + threadIdx.x;  // b*LP*C + t*C + c
  const int c = idx & 63;
  const int row = idx >> 6;  // b*LP + t
  const int b = row / LP;
  const int t = row - b * LP;
  const int s = refl(t - 64);
  pad[idx] = seq[(b * L_ + s) * C_ + c];
}

// ws layout (floats): [0..1023] sum_re, [1024..2047] sum_im, [2048..3071] sum_sq,
//                     [4096 ..] padded input [16][640][64]
// ---------------- Pass A: Parseval reduce (on padded input) ----------------
__global__ void __launch_bounds__(256)
fe_reduce_kernel(const float* __restrict__ pad, float* __restrict__ acc) {
  const int p = blockIdx.x * 4 + (threadIdx.x >> 6);
  const int b = __builtin_amdgcn_readfirstlane(p >> 9);
  const int l = __builtin_amdgcn_readfirstlane(p & (L_ - 1));
  const int c = threadIdx.x & 63;

  const float* base = pad + ((size_t)(b * LP + l)) * C_ + c;

  float x0 = 0.f, x64 = 0.f, p2 = 0.f, d2 = 0.f;
#pragma unroll
  for (int n = 0; n < 128; ++n) {
    const float v = base[n * C_];
    x0 += TBL.win[n] * v;
    x64 += TBL.walt[n] * v;
    const float wv = TBL.w2[n] * v;
    p2 += wv * v;
    d2 += TBL.wg[n] * v;
  }

  const float sre = 0.5f * (x0 + x64);
  const float sim = -d2;
  const float ssq = 64.0f * p2 + 0.5f * (x0 * x0 + x64 * x64);

  __shared__ float red[3][256];
  const int tid = threadIdx.x;
  red[0][tid] = sre;
  red[1][tid] = sim;
  red[2][tid] = ssq;
  __syncthreads();
  if (tid < 64) {
    const float a0 = red[0][tid] + red[0][tid + 64] + red[0][tid + 128] + red[0][tid + 192];
    const float a1 = red[1][tid] + red[1][tid + 64] + red[1][tid + 128] + red[1][tid + 192];
    const float a2 = red[2][tid] + red[2][tid + 64] + red[2][tid + 128] + red[2][tid + 192];
    const int g = b * C_ + tid;
    unsafeAtomicAdd(&acc[g], a0);
    unsafeAtomicAdd(&acc[1024 + g], a1);
    unsafeAtomicAdd(&acc[2048 + g], a2);
  }
}

// ---------------- Pass B: monolithic FFT + write, cached stores ----------------
__global__ void __launch_bounds__(256, 3)
fe_write_kernel(const float* __restrict__ pad, const float* __restrict__ acc,
                float* __restrict__ out) {
  const int tid = threadIdx.x;
  const int p = blockIdx.x * 4 + (tid >> 6);
  const int b = __builtin_amdgcn_readfirstlane(p >> 9);
  const int l = __builtin_amdgcn_readfirstlane(p & (L_ - 1));
  const int c = tid & 63;

  // fused finalize: true-scale sums -> constants matching the 2x bins
  const int g = b * C_ + c;
  const float invN = 1.0f / (float)NLF;
  const float sr = acc[g] * invN;
  const float si = acc[1024 + g] * invN;
  const float qq = acc[2048 + g] * invN;
  const float var = qq - sr * sr - si * si;
  const float mr = 2.0f * sr;
  const float mi = 2.0f * si;
  const float is = 0.5f * rsqrtf(var);

  const float* base = pad + ((size_t)(b * LP + l)) * C_ + c;

  // ---- load in bit-reversed order, pack even/odd, apply window ----
  float zr[64], zi[64];
#pragma unroll
  for (int n = 0; n < 64; ++n) {
    const int m = bitrev6(n);
    zr[n] = TBL.win[2 * m] * base[(2 * m) * C_];
    zi[n] = TBL.win[2 * m + 1] * base[(2 * m + 1) * C_];
  }

  // ---- 64-point complex DIT FFT, fully unrolled, literal twiddles ----
#pragma unroll
  for (int s = 0; s < 6; ++s) {
    const int half = 1 << s;
    const int len = half << 1;
#pragma unroll
    for (int j = 0; j < half; ++j) {
      const float wr = TBL.twr[j << (5 - s)];
      const float wi = TBL.twi[j << (5 - s)];
#pragma unroll
      for (int base2 = 0; base2 < 64; base2 += len) {
        const int a = base2 + j;
        const int b2 = a + half;
        const float tr = wr * zr[b2] - wi * zi[b2];
        const float ti = wr * zi[b2] + wi * zr[b2];
        zr[b2] = zr[a] - tr;
        zi[b2] = zi[a] - ti;
        zr[a] += tr;
        zi[a] += ti;
      }
    }
  }

  float* obase = out + (((size_t)(b * L_ + l)) * F_) * C_ + c;
  auto emit = [&](int f, float Xr, float Xi) {
    const float dr = Xr - mr;
    const float di = Xi - mi;
    const float amp = fast_sqrt(__builtin_fmaf(dr, dr, di * di)) * is;
    obase[(size_t)f * C_] = amp;  // R13: plain cached store (was nontemporal)
  };

  // ---- real-FFT unpack (bins scaled 2x; compensated in mr/mi/is) ----
  emit(0, 2.0f * (zr[0] + zi[0]), 0.0f);
  emit(64, 2.0f * (zr[0] - zi[0]), 0.0f);
  emit(32, 2.0f * zr[32], -2.0f * zi[32]);
#pragma unroll
  for (int k = 1; k < 32; ++k) {
    const float cr = TBL.cur[k], ci = TBL.cui[k];
    const float Er = zr[k] + zr[64 - k];
    const float Ei = zi[k] - zi[64 - k];
    const float Or = zi[k] + zi[64 - k];
    const float Oi = zr[64 - k] - zr[k];
    const float wOr = cr * Or - ci * Oi;
    const float wOi = cr * Oi + ci * Or;
    emit(k, Er + wOr, Ei + wOi);
    emit(64 - k, Er - wOr, wOi - Ei);
  }
}

extern "C" void kernel_launch(void* const* d_in, const int* in_sizes, int n_in,
                              void* d_out, int out_size, void* d_ws, size_t ws_size,
                              hipStream_t stream) {
  const float* seq = (const float*)d_in[0];
  float* out = (float*)d_out;
  float* ws = (float*)d_ws;
  float* acc = ws;          // 3072 floats
  float* pad = ws + 4096;   // 16*640*64 = 655360 floats (2.62 MB)

  hipMemsetAsync(acc, 0, 3072 * sizeof(float), stream);

  fe_pad_kernel<<<(B_ * LP * C_) / 256, 256, 0, stream>>>(seq, pad);
  const int nblocks = (B_ * L_) / 4;  // 2048 blocks, 4 (b,l) pairs each
  fe_reduce_kernel<<<nblocks, 256, 0, stream>>>(pad, acc);
  fe_write_kernel<<<nblocks, 256, 0, stream>>>(pad, acc, out);
}

// Round 14
// 56.961 us; speedup vs baseline: 1.3151x; 1.1042x over previous
//
#include <hip/hip_runtime.h>
#include <math.h>

// FreqEmbedding: seq [16,512,64] f32 -> out [16,512,65,64] f32
// reflect-pad(64) -> hanning(128) frames -> rfft(128) -> complex standardize
// over (L,F) per (B,C) -> abs.
//
// Pass 0 (pad): materialize reflect-padded input [16,640,64]; ALSO zeroes
//   the 3072-float acc region (drops the memset dispatch; reduce runs after).
// Pass A (reduce): Parseval + symmetry identities (4 dot products) (proven).
// Pass B (write): monolithic 64-pt FFT per thread (min VALU; all 6
//   restructures R6/R9-R12 regressed), float2-interleaved state so the
//   packed-math combiner can emit v_pk_{add,sub,fma}_f32 on butterfly
//   add/subs (halves issue count on ~40% of FFT ops, shrinks I-fetch).
//   nt-stores + (256,3): best proven config (R8 = 61.6us).

#define B_ 16
#define L_ 512
#define C_ 64
#define W_ 128
#define F_ 65
#define LP 640  // padded length
#define NLF (L_ * F_)  // 33280

// ---------- compile-time trig tables (fold to VALU literals) ----------
constexpr double kPI = 3.14159265358979323846;

constexpr double csin_(double x) {
  while (x > kPI) x -= 2.0 * kPI;
  while (x < -kPI) x += 2.0 * kPI;
  double t = x, s = x, x2 = x * x;
  for (int i = 1; i <= 24; ++i) {
    t *= -x2 / ((2.0 * i) * (2.0 * i + 1.0));
    s += t;
  }
  return s;
}
constexpr double ccos_(double x) { return csin_(kPI / 2.0 - x); }

constexpr int bitrev6(int n) {
  int r = 0;
  for (int i = 0; i < 6; ++i) r |= ((n >> i) & 1) << (5 - i);
  return r;
}

struct Tables {
  float win[128];         // hanning w_n
  float walt[128];        // (-1)^n w_n
  float w2[128];          // w_n^2
  float wg[128];          // w_n * G_n
  float twr[32], twi[32]; // exp(-2*pi*i*j/64)
  float cur[32], cui[32]; // exp(-2*pi*i*k/128), k=0..31
  constexpr Tables() : win(), walt(), w2(), wg(), twr(), twi(), cur(), cui() {
    for (int n = 0; n < 128; ++n) {
      const double wd = 0.5 - 0.5 * ccos_(2.0 * kPI * n / 127.0);
      win[n] = (float)wd;
      walt[n] = (n & 1) ? (float)(-wd) : (float)wd;
      w2[n] = (float)(wd * wd);
      if (n == 0) {
        wg[n] = 0.0f;
      } else {
        // G_n = sin(pi n/2) * sin(65 pi n/128) / sin(pi n/128)
        const double G = csin_(kPI * n / 2.0) * csin_(65.0 * kPI * n / 128.0) /
                         csin_(kPI * n / 128.0);
        wg[n] = (float)(wd * G);
      }
    }
    for (int j = 0; j < 32; ++j) {
      twr[j] = (float)ccos_(2.0 * kPI * j / 64.0);
      twi[j] = (float)(-csin_(2.0 * kPI * j / 64.0));
    }
    for (int k = 0; k < 32; ++k) {
      cur[k] = (float)ccos_(2.0 * kPI * k / 128.0);
      cui[k] = (float)(-csin_(2.0 * kPI * k / 128.0));
    }
  }
};
constexpr Tables TBL{};

// branchless reflect into [0,512) for t in [-64, 575]
__device__ __forceinline__ int refl(int t) {
  const int a = max(t, -t);
  return min(a, 1022 - a);
}

__device__ __forceinline__ float fast_sqrt(float x) {
  float r;
  asm("v_sqrt_f32 %0, %1" : "=v"(r) : "v"(x));
  return r;
}

// ---------------- Pass 0: pad materialize + acc zero ----------------
__global__ void __launch_bounds__(256)
fe_pad_kernel(const float* __restrict__ seq, float* __restrict__ pad,
              float* __restrict__ acc) {
  const int idx = blockIdx.x * 256 + threadIdx.x;  // b*LP*C + t*C + c
  if (idx < 3072) acc[idx] = 0.0f;  // zero accumulators (reduce runs after)
  const int c = idx & 63;
  const int row = idx >> 6;  // b*LP + t
  const int b = row / LP;
  const int t = row - b * LP;
  const int s = refl(t - 64);
  pad[idx] = seq[(b * L_ + s) * C_ + c];
}

// ws layout (floats): [0..1023] sum_re, [1024..2047] sum_im, [2048..3071] sum_sq,
//                     [4096 ..] padded input [16][640][64]
// ---------------- Pass A: Parseval reduce (on padded input) ----------------
__global__ void __launch_bounds__(256)
fe_reduce_kernel(const float* __restrict__ pad, float* __restrict__ acc) {
  const int p = blockIdx.x * 4 + (threadIdx.x >> 6);
  const int b = __builtin_amdgcn_readfirstlane(p >> 9);
  const int l = __builtin_amdgcn_readfirstlane(p & (L_ - 1));
  const int c = threadIdx.x & 63;

  const float* base = pad + ((size_t)(b * LP + l)) * C_ + c;

  float x0 = 0.f, x64 = 0.f, p2 = 0.f, d2 = 0.f;
#pragma unroll
  for (int n = 0; n < 128; ++n) {
    const float v = base[n * C_];
    x0 += TBL.win[n] * v;
    x64 += TBL.walt[n] * v;
    const float wv = TBL.w2[n] * v;
    p2 += wv * v;
    d2 += TBL.wg[n] * v;
  }

  const float sre = 0.5f * (x0 + x64);
  const float sim = -d2;
  const float ssq = 64.0f * p2 + 0.5f * (x0 * x0 + x64 * x64);

  __shared__ float red[3][256];
  const int tid = threadIdx.x;
  red[0][tid] = sre;
  red[1][tid] = sim;
  red[2][tid] = ssq;
  __syncthreads();
  if (tid < 64) {
    const float a0 = red[0][tid] + red[0][tid + 64] + red[0][tid + 128] + red[0][tid + 192];
    const float a1 = red[1][tid] + red[1][tid + 64] + red[1][tid + 128] + red[1][tid + 192];
    const float a2 = red[2][tid] + red[2][tid + 64] + red[2][tid + 128] + red[2][tid + 192];
    const int g = b * C_ + tid;
    unsafeAtomicAdd(&acc[g], a0);
    unsafeAtomicAdd(&acc[1024 + g], a1);
    unsafeAtomicAdd(&acc[2048 + g], a2);
  }
}

// ---------------- Pass B: monolithic FFT (float2 packed) + write ----------------
__global__ void __launch_bounds__(256, 3)
fe_write_kernel(const float* __restrict__ pad, const float* __restrict__ acc,
                float* __restrict__ out) {
  const int tid = threadIdx.x;
  const int p = blockIdx.x * 4 + (tid >> 6);
  const int b = __builtin_amdgcn_readfirstlane(p >> 9);
  const int l = __builtin_amdgcn_readfirstlane(p & (L_ - 1));
  const int c = tid & 63;

  // fused finalize: true-scale sums -> constants matching the 2x bins
  const int g = b * C_ + c;
  const float invN = 1.0f / (float)NLF;
  const float sr = acc[g] * invN;
  const float si = acc[1024 + g] * invN;
  const float qq = acc[2048 + g] * invN;
  const float var = qq - sr * sr - si * si;
  const float mr = 2.0f * sr;
  const float mi = 2.0f * si;
  const float is = 0.5f * rsqrtf(var);

  const float* base = pad + ((size_t)(b * LP + l)) * C_ + c;

  // ---- load in bit-reversed order, pack even/odd, apply window ----
  float2 z[64];
#pragma unroll
  for (int n = 0; n < 64; ++n) {
    const int m = bitrev6(n);
    z[n].x = TBL.win[2 * m] * base[(2 * m) * C_];
    z[n].y = TBL.win[2 * m + 1] * base[(2 * m + 1) * C_];
  }

  // ---- 64-point complex DIT FFT, fully unrolled, literal twiddles.
  //      Adjacent paired field ops -> v_pk_{add,sub,fma}_f32 candidates. ----
#pragma unroll
  for (int s = 0; s < 6; ++s) {
    const int half = 1 << s;
    const int len = half << 1;
#pragma unroll
    for (int j = 0; j < half; ++j) {
      const float wr = TBL.twr[j << (5 - s)];
      const float wi = TBL.twi[j << (5 - s)];
#pragma unroll
      for (int base2 = 0; base2 < 64; base2 += len) {
        const int a = base2 + j;
        const int b2 = a + half;
        const float tr = wr * z[b2].x - wi * z[b2].y;
        const float ti = wr * z[b2].y + wi * z[b2].x;
        const float ax = z[a].x, ay = z[a].y;
        z[b2].x = ax - tr;        // pk_sub pair
        z[b2].y = ay - ti;
        z[a].x = ax + tr;         // pk_add pair
        z[a].y = ay + ti;
      }
    }
  }

  float* obase = out + (((size_t)(b * L_ + l)) * F_) * C_ + c;
  auto emit = [&](int f, float Xr, float Xi) {
    const float dr = Xr - mr;
    const float di = Xi - mi;
    const float amp = fast_sqrt(__builtin_fmaf(dr, dr, di * di)) * is;
    __builtin_nontemporal_store(amp, &obase[(size_t)f * C_]);
  };

  // ---- real-FFT unpack (bins scaled 2x; compensated in mr/mi/is) ----
  emit(0, 2.0f * (z[0].x + z[0].y), 0.0f);
  emit(64, 2.0f * (z[0].x - z[0].y), 0.0f);
  emit(32, 2.0f * z[32].x, -2.0f * z[32].y);
#pragma unroll
  for (int k = 1; k < 32; ++k) {
    const float cr = TBL.cur[k], ci = TBL.cui[k];
    const float Er = z[k].x + z[64 - k].x;
    const float Ei = z[k].y - z[64 - k].y;
    const float Or = z[k].y + z[64 - k].y;
    const float Oi = z[64 - k].x - z[k].x;
    const float wOr = cr * Or - ci * Oi;
    const float wOi = cr * Oi + ci * Or;
    emit(k, Er + wOr, Ei + wOi);
    emit(64 - k, Er - wOr, wOi - Ei);
  }
}

extern "C" void kernel_launch(void* const* d_in, const int* in_sizes, int n_in,
                              void* d_out, int out_size, void* d_ws, size_t ws_size,
                              hipStream_t stream) {
  const float* seq = (const float*)d_in[0];
  float* out = (float*)d_out;
  float* ws = (float*)d_ws;
  float* acc = ws;          // 3072 floats
  float* pad = ws + 4096;   // 16*640*64 = 655360 floats (2.62 MB)

  // 3 dispatches total (memset folded into pad kernel)
  fe_pad_kernel<<<(B_ * LP * C_) / 256, 256, 0, stream>>>(seq, pad, acc);
  const int nblocks = (B_ * L_) / 4;  // 2048 blocks, 4 (b,l) pairs each
  fe_reduce_kernel<<<nblocks, 256, 0, stream>>>(pad, acc);
  fe_write_kernel<<<nblocks, 256, 0, stream>>>(pad, acc, out);
}